// Round 8
// baseline (212.575 us; speedup 1.0000x reference)
//
#include <hip/hip_runtime.h>

typedef unsigned short u16;
typedef __bf16 bf16_t;
typedef bf16_t bf16x8 __attribute__((ext_vector_type(8)));
typedef float f32x4 __attribute__((ext_vector_type(4)));
typedef u16 u16x8 __attribute__((ext_vector_type(8)));
typedef u16 u16x4 __attribute__((ext_vector_type(4)));
typedef unsigned u32x4 __attribute__((ext_vector_type(4)));

#define B_ 8
#define S_ 4096
#define H_ 768
#define M_ (B_ * S_)

// round-to-nearest-even fp32 -> bf16
__device__ __forceinline__ u16 f2b(float f) {
  unsigned u = __float_as_uint(f);
  u += 0x7fffu + ((u >> 16) & 1u);
  return (u16)(u >> 16);
}

// async global->LDS, 16B per lane; lds base must be wave-uniform
__device__ __forceinline__ void gl_lds16(const void* g, void* l) {
  __builtin_amdgcn_global_load_lds(
      (const __attribute__((address_space(1))) void*)g,
      (__attribute__((address_space(3))) void*)l, 16, 0, 0);
}

// ---------------------------------------------------------------------------
// Kernel 1: WbT[n][k] bf16 (n: 0-63=q,64-127=k,128-191=v). Coalesced reads,
// LDS transpose, coalesced writes. 36 blocks.
// ---------------------------------------------------------------------------
__global__ __launch_bounds__(256) void wconv_k(const float* __restrict__ Wq,
                                               const float* __restrict__ Wk,
                                               const float* __restrict__ Wv,
                                               u16* __restrict__ WbT) {
  __shared__ float wt[64 * 68];
  const int tid = threadIdx.x;
  int mat = blockIdx.x / 12;
  int k0 = (blockIdx.x % 12) * 64;
  const float* W = (mat == 0) ? Wq : ((mat == 1) ? Wk : Wv);
  int r = tid >> 2, c0 = (tid & 3) * 16;
  const float* src = W + (size_t)(k0 + r) * 64 + c0;
#pragma unroll
  for (int j = 0; j < 16; j += 4)
    *(float4*)&wt[r * 68 + c0 + j] = *(const float4*)(src + j);
  __syncthreads();
  int d = tid >> 2;
  u16* dst = WbT + (size_t)(mat * 64 + d) * 768 + k0 + c0;
  u16x8 o0, o1;
#pragma unroll
  for (int j = 0; j < 8; ++j) o0[j] = f2b(wt[(c0 + j) * 68 + d]);
#pragma unroll
  for (int j = 0; j < 8; ++j) o1[j] = f2b(wt[(c0 + 8 + j) * 68 + d]);
  *(u16x8*)dst = o0;
  *(u16x8*)(dst + 8) = o1;
}

// ---------------------------------------------------------------------------
// Kernel 2: QKV projection, 128 rows/block, 512 threads (8 waves =
// 2 row-halves x 4 col-quarters). DEPTH-2 register prefetch (two named reg
// sets A/B, static indexing): loads for tile kt+2 are issued at tile kt, so
// ~32 KB/CU stays in flight across each barrier — qkv is HBM-BW-bound on the
// x read (96 MB, 15 us floor) and depth-1 under-filled the pipe.
// Double-buffered LDS, ONE barrier/iter. q pre-scaled by 0.125*log2(e).
// K,Q stored [s][d]; V stored transposed [d][s] with t permuted within each
// 64-block by pi: [b5|qd|jh|jl] -> [b5|jh|qd|jl] so attention's PV A-fragment
// needs NO cross-lane P redistribution.
// ---------------------------------------------------------------------------
__global__ __launch_bounds__(512) void qkv_k(const float* __restrict__ x,
                                             const u16* __restrict__ WbT,
                                             const float* __restrict__ bq,
                                             const float* __restrict__ bk,
                                             const float* __restrict__ bv,
                                             u16* __restrict__ qb,
                                             u16* __restrict__ kb,
                                             u16* __restrict__ vbT) {
  __shared__ __align__(16) u16 smem[2 * 5120 + 2 * 7680];  // xs[2]:128x40, ws[2]:192x40
  const int tid = threadIdx.x;  // 0..511
  const int w = tid >> 6, ln = tid & 15, qd = (tid >> 4) & 3;
  const int rh = w >> 2;   // row half: rows rh*64..rh*64+63
  const int wc = w & 3;    // col quarter: cols wc*48..wc*48+47
  const int row0 = blockIdx.x * 128;

  const f32x4 z4 = {0.f, 0.f, 0.f, 0.f};
  f32x4 acc[4][3];
#pragma unroll
  for (int rt = 0; rt < 4; ++rt)
#pragma unroll
    for (int ct = 0; ct < 3; ++ct) acc[rt][ct] = z4;

  const int xr = tid >> 2, xc = (tid & 3) * 8;  // 128 rows x 32 cols of x
  const int wr = tid >> 2, woff = (tid & 3) * 8;        // WbT cols 0..127
  const int c2 = 512 + tid, wr2 = c2 >> 2, woff2 = (c2 & 3) * 8;  // cols 128..191

  float4 xa0, xa1, xb0, xb1;
  u16x8 wa0, wa1, wb0, wb1;

  auto loadA = [&](int kt) {
    const float* sx = x + (size_t)(row0 + xr) * 768 + kt * 32 + xc;
    xa0 = *(const float4*)sx;
    xa1 = *(const float4*)(sx + 4);
    wa0 = *(const u16x8*)(WbT + (size_t)wr * 768 + kt * 32 + woff);
    if (tid < 256)
      wa1 = *(const u16x8*)(WbT + (size_t)wr2 * 768 + kt * 32 + woff2);
  };
  auto loadB = [&](int kt) {
    const float* sx = x + (size_t)(row0 + xr) * 768 + kt * 32 + xc;
    xb0 = *(const float4*)sx;
    xb1 = *(const float4*)(sx + 4);
    wb0 = *(const u16x8*)(WbT + (size_t)wr * 768 + kt * 32 + woff);
    if (tid < 256)
      wb1 = *(const u16x8*)(WbT + (size_t)wr2 * 768 + kt * 32 + woff2);
  };
  auto stage = [&](u16* xs, u16* wsb, const float4& f0, const float4& f1,
                   const u16x8& w0, const u16x8& w1) {
    u16x8 v;
    v[0] = f2b(f0.x); v[1] = f2b(f0.y); v[2] = f2b(f0.z); v[3] = f2b(f0.w);
    v[4] = f2b(f1.x); v[5] = f2b(f1.y); v[6] = f2b(f1.z); v[7] = f2b(f1.w);
    *(u16x8*)&xs[xr * 40 + xc] = v;
    *(u16x8*)&wsb[wr * 40 + woff] = w0;
    if (tid < 256) *(u16x8*)&wsb[wr2 * 40 + woff2] = w1;
  };
  auto compute = [&](const u16* xs, const u16* wsb) {
    bf16x8 af[4], bfr[3];
#pragma unroll
    for (int rt = 0; rt < 4; ++rt)
      af[rt] = *(const bf16x8*)&xs[(rh * 64 + rt * 16 + ln) * 40 + qd * 8];
#pragma unroll
    for (int ct = 0; ct < 3; ++ct)
      bfr[ct] = *(const bf16x8*)&wsb[(wc * 48 + ct * 16 + ln) * 40 + qd * 8];
#pragma unroll
    for (int rt = 0; rt < 4; ++rt)
#pragma unroll
      for (int ct = 0; ct < 3; ++ct)
        acc[rt][ct] = __builtin_amdgcn_mfma_f32_16x16x32_bf16(
            af[rt], bfr[ct], acc[rt][ct], 0, 0, 0);
  };

  loadA(0);
  loadB(1);
  for (int kt = 0; kt < 24; kt += 2) {
    // even tile: stage A -> buf0, refill A from kt+2 (in flight across barrier)
    stage(smem, smem + 10240, xa0, xa1, wa0, wa1);
    if (kt + 2 < 24) loadA(kt + 2);
    __syncthreads();
    compute(smem, smem + 10240);
    // odd tile: stage B -> buf1, refill B from kt+3
    stage(smem + 5120, smem + 10240 + 7680, xb0, xb1, wb0, wb1);
    if (kt + 3 < 24) loadB(kt + 3);
    __syncthreads();
    compute(smem + 5120, smem + 10240 + 7680);
    // WAR: buf0 restage at kt+2 is separated from this compute by the
    // next even barrier; buffers alternate so one barrier/iter suffices.
  }
  __syncthreads();  // protect vt (overlaps staging buffers) against last reads

  // epilogue: q,k direct stores + v transpose via LDS reuse (64 d x 128 s)
  u16* vt = smem;  // 64*136 u16 = 17408 B, fits in smem
#pragma unroll
  for (int ct = 0; ct < 3; ++ct) {
    int col = wc * 48 + ct * 16 + ln;
    int mat = col >> 6, d = col & 63;
    if (mat < 2) {
      const float* bp = (mat == 0) ? bq : bk;
      u16* op = (mat == 0) ? qb : kb;
      float bias = bp[d];
      float scale = (mat == 0) ? 0.18033688011112042f : 1.0f;
#pragma unroll
      for (int rt = 0; rt < 4; ++rt)
#pragma unroll
        for (int r = 0; r < 4; ++r)
          op[(size_t)(row0 + rh * 64 + rt * 16 + qd * 4 + r) * 64 + d] =
              f2b((acc[rt][ct][r] + bias) * scale);
    } else {
      float bias = bv[d];
#pragma unroll
      for (int rt = 0; rt < 4; ++rt)
#pragma unroll
        for (int r = 0; r < 4; ++r)
          vt[d * 136 + rh * 64 + rt * 16 + qd * 4 + r] =
              f2b(acc[rt][ct][r] + bias);
    }
  }
  __syncthreads();
  {
    int d = tid >> 3, so = (tid & 7) * 16;  // 64 d x 128 s, 16 u16/thread
    int b = row0 >> 12, s0 = row0 & 4095;
    u16* dst = vbT + ((size_t)b * 64 + d) * 4096 + s0;
    // permuted store: position t_slot gets V row t_nat = pi(t_slot),
    // permutation applied within each 64-block (bit6 passes through)
#pragma unroll
    for (int g = 0; g < 4; ++g) {
      int ts = so + g * 4;
      int tn = (ts & 0x40) | (ts & 0x23) | ((ts & 4) << 2) | ((ts & 0x18) >> 1);
      *(u16x4*)(dst + ts) = *(const u16x4*)&vt[d * 136 + tn];
    }
  }
}

// ---------------------------------------------------------------------------
// Kernel 3: causal flash attention, 128 q-rows/block, 32 q-rows/wave.
// 2 LDS buffers (32 KB), <=8-tile chunks -> 1152 blocks. Depth-1 schedule:
// {vmcnt(0); barrier; prefetch(nxt); compute(cur)}. Swapped QK^T
// (S^T = mfma(K,Q)); V pre-permuted so the PV A-fragment is each lane's own
// exp'd scores packed via v_cvt_pk_bf16_f32 — P never touches LDS.
// nc==1 blocks (qi<=3) write out directly (in-wave shfl for l; no fences).
// ---------------------------------------------------------------------------
__global__ __launch_bounds__(256) void attn_k(const u16* __restrict__ qb,
                                              const u16* __restrict__ kb,
                                              const u16* __restrict__ vbT,
                                              float* __restrict__ po,
                                              float* __restrict__ pl,
                                              float* __restrict__ out) {
  __shared__ __align__(16) u16 ks[2][4096];
  __shared__ __align__(16) u16 vs[2][4096];
  const int tid = threadIdx.x;
  const int wv = tid >> 6, ln = tid & 15, qd = (tid >> 4) & 3;
  const int id = blockIdx.x;  // 1152 blocks, longest chunks first
  const int b = id & 7;
  const int j = id >> 3;  // 0..143
  int qi = 31, acc = 0;
  for (;;) {
    int ncq = (2 * qi + 9) >> 3;
    if (acc + ncq <= j) { acc += ncq; --qi; } else break;
  }
  const int c = j - acc;                 // chunk index 0..nc-1
  const int ntiles = 2 * qi + 2;
  const int nc = (2 * qi + 9) >> 3;
  const int bas = ntiles / nc, rem = ntiles % nc;
  const int tstart = c * bas + (c < rem ? c : rem);
  const int tcount = bas + (c < rem ? 1 : 0);  // <= 8
  const int q0 = qi * 128;
  const int q0w = q0 + wv * 32;
  const int base = b * S_;
  const u16* kg = kb + (size_t)base * 64;
  const u16* vg = vbT + (size_t)b * 64 * 4096;

  bf16x8 qf[2][2];
#pragma unroll
  for (int qt = 0; qt < 2; ++qt) {
    const u16* qrow = qb + (size_t)(base + q0w + qt * 16 + ln) * 64;
    qf[qt][0] = *(const bf16x8*)(qrow + qd * 8);
    qf[qt][1] = *(const bf16x8*)(qrow + 32 + qd * 8);
  }
  const f32x4 z4 = {0.f, 0.f, 0.f, 0.f};
  f32x4 o0[4] = {z4, z4, z4, z4};
  f32x4 o1[4] = {z4, z4, z4, z4};
  float lq0 = 0.f, lq1 = 0.f;
  const int lr = (tid & 63) >> 3, csl = tid & 7;

  auto prefetch = [&](int bufi, int tile) {
    const u16* kt_ = kg + (size_t)tile * 4096;
    const u16* vt_ = vg + tile * 64;
#pragma unroll
    for (int i = 0; i < 2; ++i) {
      int r0 = wv * 16 + i * 8;
      int r = r0 + lr;
      int cc = csl ^ (r & 7);
      gl_lds16(kt_ + r * 64 + cc * 8, &ks[bufi][r0 * 64]);
      gl_lds16(vt_ + (size_t)r * 4096 + cc * 8, &vs[bufi][r0 * 64]);
    }
  };

  prefetch(0, tstart);
  int cur = 0;
  for (int it = 0; it < tcount; ++it) {
    // own cur-tile loads done -> barrier: everyone's cur landed AND all
    // waves finished computing from the other buffer (WAR-safe prefetch).
    asm volatile("s_waitcnt vmcnt(0)" ::: "memory");
    __builtin_amdgcn_s_barrier();
    if (it + 1 < tcount) prefetch(cur ^ 1, tstart + it + 1);
    const int t0a = (tstart + it) * 64;

    if (t0a <= q0w + 31) {  // wave-uniform: at least one live row
      f32x4 s0[4] = {z4, z4, z4, z4};
      f32x4 s1[4] = {z4, z4, z4, z4};
      // S^T = K * Q^T : lane holds col q=ln, rows t = nt*16 + qd*4 + r
      __builtin_amdgcn_s_setprio(1);
#pragma unroll
      for (int kc = 0; kc < 2; ++kc) {
        int cs = (kc * 4 + qd) ^ (ln & 7);
#pragma unroll
        for (int nt = 0; nt < 4; ++nt) {
          bf16x8 kf = *(const bf16x8*)&ks[cur][(nt * 16 + ln) * 64 + cs * 8];
          s0[nt] = __builtin_amdgcn_mfma_f32_16x16x32_bf16(kf, qf[0][kc], s0[nt], 0, 0, 0);
          s1[nt] = __builtin_amdgcn_mfma_f32_16x16x32_bf16(kf, qf[1][kc], s1[nt], 0, 0, 0);
        }
      }
      __builtin_amdgcn_s_setprio(0);
      if (t0a + 63 > q0w) {  // diagonal overlap: causal mask (t > q -> -inf)
#pragma unroll
        for (int nt = 0; nt < 4; ++nt) {
          int tg = t0a + nt * 16 + qd * 4;
#pragma unroll
          for (int r = 0; r < 4; ++r) {
            if (tg + r > q0w + ln) s0[nt][r] = -INFINITY;
            if (tg + r > q0w + 16 + ln) s1[nt][r] = -INFINITY;
          }
        }
      }
      // exp; pack in-register (V pre-permuted: A-frag = own values in order)
      float p0[4][4], p1[4][4];
#pragma unroll
      for (int nt = 0; nt < 4; ++nt)
#pragma unroll
        for (int r = 0; r < 4; ++r) {
          p0[nt][r] = __builtin_amdgcn_exp2f(s0[nt][r]);
          p1[nt][r] = __builtin_amdgcn_exp2f(s1[nt][r]);
          lq0 += p0[nt][r];
          lq1 += p1[nt][r];
        }
      unsigned pk0[8], pk1[8];
#pragma unroll
      for (int i = 0; i < 8; ++i) {  // word i: pair (p[i>>1][(i&1)*2], +1)
        int nt = i >> 1, rb = (i & 1) * 2;
        asm("v_cvt_pk_bf16_f32 %0, %1, %2"
            : "=v"(pk0[i]) : "v"(p0[nt][rb]), "v"(p0[nt][rb + 1]));
        asm("v_cvt_pk_bf16_f32 %0, %1, %2"
            : "=v"(pk1[i]) : "v"(p1[nt][rb]), "v"(p1[nt][rb + 1]));
      }
      // PV: A = packed P (registers), B = permuted-V fragments from LDS
      __builtin_amdgcn_s_setprio(1);
#pragma unroll
      for (int kc = 0; kc < 2; ++kc) {
        u32x4 w0 = {pk0[4 * kc], pk0[4 * kc + 1], pk0[4 * kc + 2], pk0[4 * kc + 3]};
        u32x4 w1 = {pk1[4 * kc], pk1[4 * kc + 1], pk1[4 * kc + 2], pk1[4 * kc + 3]};
        bf16x8 a0 = __builtin_bit_cast(bf16x8, w0);
        bf16x8 a1 = __builtin_bit_cast(bf16x8, w1);
        int cs = (kc * 4 + qd) ^ (ln & 7);
#pragma unroll
        for (int nt = 0; nt < 4; ++nt) {
          bf16x8 vf = *(const bf16x8*)&vs[cur][(nt * 16 + ln) * 64 + cs * 8];
          o0[nt] = __builtin_amdgcn_mfma_f32_16x16x32_bf16(a0, vf, o0[nt], 0, 0, 0);
          o1[nt] = __builtin_amdgcn_mfma_f32_16x16x32_bf16(a1, vf, o1[nt], 0, 0, 0);
        }
      }
      __builtin_amdgcn_s_setprio(0);
    }
    cur ^= 1;
  }

  // l-sums: reduce across the 4 qd lane-groups; lane L holds l for q = L&15
  lq0 += __shfl_xor(lq0, 16);
  lq0 += __shfl_xor(lq0, 32);
  lq1 += __shfl_xor(lq1, 16);
  lq1 += __shfl_xor(lq1, 32);

  if (nc == 1) {  // qi<=3: write final output directly, no partial round-trip
    float li0[4], li1[4];
#pragma unroll
    for (int r = 0; r < 4; ++r) {
      li0[r] = __shfl(lq0, qd * 4 + r);
      li1[r] = __shfl(lq1, qd * 4 + r);
    }
#pragma unroll
    for (int r = 0; r < 4; ++r) {
      int row0 = base + q0w + qd * 4 + r;
      int row1 = row0 + 16;
      float i0 = 1.0f / li0[r], i1 = 1.0f / li1[r];
#pragma unroll
      for (int nt = 0; nt < 4; ++nt) {
        out[(size_t)row0 * 64 + nt * 16 + ln] = o0[nt][r] * i0;
        out[(size_t)row1 * 64 + nt * 16 + ln] = o1[nt][r] * i1;
      }
    }
    return;
  }

  float* op = po + (size_t)c * 2097152;
  float* lpt = pl + (size_t)c * 32768;
#pragma unroll
  for (int r = 0; r < 4; ++r) {
    int row0 = base + q0w + qd * 4 + r;
    int row1 = row0 + 16;
#pragma unroll
    for (int nt = 0; nt < 4; ++nt) {
      op[(size_t)row0 * 64 + nt * 16 + ln] = o0[nt][r];
      op[(size_t)row1 * 64 + nt * 16 + ln] = o1[nt][r];
    }
  }
  if (qd == 0) {
    lpt[base + q0w + ln] = lq0;
    lpt[base + q0w + 16 + ln] = lq1;
  }
}

// ---------------------------------------------------------------------------
// Kernel 4: combine up to 8 partials: out = sum(o_c) / sum(l_c), c < nc(qi).
// nc==1 rows (qi<=3) were written directly by attn_k — skip them.
// ---------------------------------------------------------------------------
__global__ __launch_bounds__(256) void comb_k(const float* __restrict__ po,
                                              const float* __restrict__ pl,
                                              float* __restrict__ out) {
  int idx = blockIdx.x * 256 + threadIdx.x;  // 524288 threads
  int r = idx >> 4, d0 = (idx & 15) * 4;
  int qi = (r & 4095) >> 7;
  int nc = (2 * qi + 9) >> 3;
  if (nc == 1) return;  // attn wrote these rows directly
  const float* p = po + (size_t)r * 64 + d0;
  float4 a = *(const float4*)p;
  float l = pl[r];
  for (int cc = 1; cc < nc; ++cc) {
    float4 t = *(const float4*)(p + (size_t)cc * 2097152);
    a.x += t.x; a.y += t.y; a.z += t.z; a.w += t.w;
    l += pl[r + cc * 32768];
  }
  float inv = 1.0f / l;
  a.x *= inv; a.y *= inv; a.z *= inv; a.w *= inv;
  *(float4*)(out + (size_t)r * 64 + d0) = a;
}

// ---------------------------------------------------------------------------
extern "C" void kernel_launch(void* const* d_in, const int* in_sizes, int n_in,
                              void* d_out, int out_size, void* d_ws, size_t ws_size,
                              hipStream_t stream) {
  const float* x  = (const float*)d_in[0];
  const float* Wq = (const float*)d_in[1];
  const float* bq = (const float*)d_in[2];
  const float* Wk = (const float*)d_in[3];
  const float* bk = (const float*)d_in[4];
  const float* Wv = (const float*)d_in[5];
  const float* bv = (const float*)d_in[6];
  float* out = (float*)d_out;

  char* wsp = (char*)d_ws;
  u16* WbT = (u16*)wsp;                            //  294912 B
  u16* qb  = (u16*)(wsp + 294912);                 // 4 MiB
  u16* kb  = (u16*)(wsp + 4489216);                // 4 MiB
  u16* vbT = (u16*)(wsp + 8683520);                // 4 MiB (transposed+permuted)
  float* po = (float*)(wsp + 12877824);            // 8 x 8 MiB partial O slabs
  float* pl = (float*)(wsp + 79986688);            // 8 x 128 KiB partial l slabs

  hipLaunchKernelGGL(wconv_k, dim3(36), dim3(256), 0, stream, Wq, Wk, Wv, WbT);
  hipLaunchKernelGGL(qkv_k, dim3(256), dim3(512), 0, stream,
                     x, WbT, bq, bk, bv, qb, kb, vbT);
  hipLaunchKernelGGL(attn_k, dim3(1152), dim3(256), 0, stream,
                     qb, kb, vbT, po, pl, out);
  hipLaunchKernelGGL(comb_k, dim3(2048), dim3(256), 0, stream,
                     po, pl, out);
}

// Round 9
// 207.886 us; speedup vs baseline: 1.0226x; 1.0226x over previous
//
#include <hip/hip_runtime.h>

typedef unsigned short u16;
typedef __bf16 bf16_t;
typedef bf16_t bf16x8 __attribute__((ext_vector_type(8)));
typedef float f32x4 __attribute__((ext_vector_type(4)));
typedef u16 u16x8 __attribute__((ext_vector_type(8)));
typedef u16 u16x4 __attribute__((ext_vector_type(4)));
typedef unsigned u32x4 __attribute__((ext_vector_type(4)));

#define B_ 8
#define S_ 4096
#define H_ 768
#define M_ (B_ * S_)

// round-to-nearest-even fp32 -> bf16
__device__ __forceinline__ u16 f2b(float f) {
  unsigned u = __float_as_uint(f);
  u += 0x7fffu + ((u >> 16) & 1u);
  return (u16)(u >> 16);
}

// async global->LDS, 16B per lane; lds base must be wave-uniform
__device__ __forceinline__ void gl_lds16(const void* g, void* l) {
  __builtin_amdgcn_global_load_lds(
      (const __attribute__((address_space(1))) void*)g,
      (__attribute__((address_space(3))) void*)l, 16, 0, 0);
}

// ---------------------------------------------------------------------------
// Kernel 1: WbT[n][k] bf16 (n: 0-63=q,64-127=k,128-191=v). Coalesced reads,
// LDS transpose, coalesced writes. 36 blocks.
// ---------------------------------------------------------------------------
__global__ __launch_bounds__(256) void wconv_k(const float* __restrict__ Wq,
                                               const float* __restrict__ Wk,
                                               const float* __restrict__ Wv,
                                               u16* __restrict__ WbT) {
  __shared__ float wt[64 * 68];
  const int tid = threadIdx.x;
  int mat = blockIdx.x / 12;
  int k0 = (blockIdx.x % 12) * 64;
  const float* W = (mat == 0) ? Wq : ((mat == 1) ? Wk : Wv);
  int r = tid >> 2, c0 = (tid & 3) * 16;
  const float* src = W + (size_t)(k0 + r) * 64 + c0;
#pragma unroll
  for (int j = 0; j < 16; j += 4)
    *(float4*)&wt[r * 68 + c0 + j] = *(const float4*)(src + j);
  __syncthreads();
  int d = tid >> 2;
  u16* dst = WbT + (size_t)(mat * 64 + d) * 768 + k0 + c0;
  u16x8 o0, o1;
#pragma unroll
  for (int j = 0; j < 8; ++j) o0[j] = f2b(wt[(c0 + j) * 68 + d]);
#pragma unroll
  for (int j = 0; j < 8; ++j) o1[j] = f2b(wt[(c0 + 8 + j) * 68 + d]);
  *(u16x8*)dst = o0;
  *(u16x8*)(dst + 8) = o1;
}

// ---------------------------------------------------------------------------
// Kernel 2: QKV projection, 128 rows/block, 512 threads (8 waves =
// 2 row-halves x 4 col-quarters). Halves WbT staging traffic, global loads
// and barriers per unit work vs the 64-row version; per-wave inner loop is
// unchanged (acc[4][3], 12 MFMA/iter). Double-buffered LDS, ONE barrier/iter
// (alternating buffers make the WAR safe), reg prefetch of tile k+1 before
// the barrier. q pre-scaled by 0.125*log2(e). K,Q stored [s][d]; V stored
// transposed [d][s] with t permuted within each 64-block by
// pi: [b5|qd|jh|jl] -> [b5|jh|qd|jl] so attention's PV A-fragment needs NO
// cross-lane P redistribution.
// ---------------------------------------------------------------------------
__global__ __launch_bounds__(512) void qkv_k(const float* __restrict__ x,
                                             const u16* __restrict__ WbT,
                                             const float* __restrict__ bq,
                                             const float* __restrict__ bk,
                                             const float* __restrict__ bv,
                                             u16* __restrict__ qb,
                                             u16* __restrict__ kb,
                                             u16* __restrict__ vbT) {
  __shared__ __align__(16) u16 smem[2 * 5120 + 2 * 7680];  // xs[2]:128x40, ws[2]:192x40
  const int tid = threadIdx.x;  // 0..511
  const int w = tid >> 6, ln = tid & 15, qd = (tid >> 4) & 3;
  const int rh = w >> 2;   // row half: rows rh*64..rh*64+63
  const int wc = w & 3;    // col quarter: cols wc*48..wc*48+47
  const int row0 = blockIdx.x * 128;

  const f32x4 z4 = {0.f, 0.f, 0.f, 0.f};
  f32x4 acc[4][3];
#pragma unroll
  for (int rt = 0; rt < 4; ++rt)
#pragma unroll
    for (int ct = 0; ct < 3; ++ct) acc[rt][ct] = z4;

  const int xr = tid >> 2, xc = (tid & 3) * 8;  // 128 rows x 32 cols of x
  float4 xf0, xf1;
  u16x8 wf0, wf1;

  auto load_t = [&](int kt) {
    const float* sx = x + (size_t)(row0 + xr) * 768 + kt * 32 + xc;
    xf0 = *(const float4*)sx;
    xf1 = *(const float4*)(sx + 4);
    {
      int r = tid >> 2, off = (tid & 3) * 8;  // WbT cols 0..127
      wf0 = *(const u16x8*)(WbT + (size_t)r * 768 + kt * 32 + off);
    }
    if (tid < 256) {  // WbT cols 128..191 (wave-uniform branch)
      int c = 512 + tid;
      int r = c >> 2, off = (c & 3) * 8;
      wf1 = *(const u16x8*)(WbT + (size_t)r * 768 + kt * 32 + off);
    }
  };

  load_t(0);
  for (int kt = 0; kt < 24; ++kt) {
    u16* xs = smem + (kt & 1) * 5120;
    u16* wsb = smem + 10240 + (kt & 1) * 7680;
    {
      u16x8 v;
      v[0] = f2b(xf0.x); v[1] = f2b(xf0.y); v[2] = f2b(xf0.z); v[3] = f2b(xf0.w);
      v[4] = f2b(xf1.x); v[5] = f2b(xf1.y); v[6] = f2b(xf1.z); v[7] = f2b(xf1.w);
      *(u16x8*)&xs[xr * 40 + xc] = v;
      {
        int r = tid >> 2, off = (tid & 3) * 8;
        *(u16x8*)&wsb[r * 40 + off] = wf0;
      }
      if (tid < 256) {
        int c = 512 + tid;
        int r = c >> 2, off = (c & 3) * 8;
        *(u16x8*)&wsb[r * 40 + off] = wf1;
      }
    }
    if (kt < 23) load_t(kt + 1);
    __syncthreads();
    bf16x8 af[4], bfr[3];
#pragma unroll
    for (int rt = 0; rt < 4; ++rt)
      af[rt] = *(const bf16x8*)&xs[(rh * 64 + rt * 16 + ln) * 40 + qd * 8];
#pragma unroll
    for (int ct = 0; ct < 3; ++ct)
      bfr[ct] = *(const bf16x8*)&wsb[(wc * 48 + ct * 16 + ln) * 40 + qd * 8];
#pragma unroll
    for (int rt = 0; rt < 4; ++rt)
#pragma unroll
      for (int ct = 0; ct < 3; ++ct)
        acc[rt][ct] = __builtin_amdgcn_mfma_f32_16x16x32_bf16(
            af[rt], bfr[ct], acc[rt][ct], 0, 0, 0);
    // no trailing barrier: next iter writes the OTHER buffer; its barrier
    // orders those writes against this iter's reads.
  }
  __syncthreads();  // protect vt (overlaps staging buffers) against last reads

  // epilogue: q,k direct stores + v transpose via LDS reuse (64 d x 128 s)
  u16* vt = smem;  // 64*136 u16 = 17408 B, fits in smem
#pragma unroll
  for (int ct = 0; ct < 3; ++ct) {
    int col = wc * 48 + ct * 16 + ln;
    int mat = col >> 6, d = col & 63;
    if (mat < 2) {
      const float* bp = (mat == 0) ? bq : bk;
      u16* op = (mat == 0) ? qb : kb;
      float bias = bp[d];
      float scale = (mat == 0) ? 0.18033688011112042f : 1.0f;
#pragma unroll
      for (int rt = 0; rt < 4; ++rt)
#pragma unroll
        for (int r = 0; r < 4; ++r)
          op[(size_t)(row0 + rh * 64 + rt * 16 + qd * 4 + r) * 64 + d] =
              f2b((acc[rt][ct][r] + bias) * scale);
    } else {
      float bias = bv[d];
#pragma unroll
      for (int rt = 0; rt < 4; ++rt)
#pragma unroll
        for (int r = 0; r < 4; ++r)
          vt[d * 136 + rh * 64 + rt * 16 + qd * 4 + r] =
              f2b(acc[rt][ct][r] + bias);
    }
  }
  __syncthreads();
  {
    int d = tid >> 3, so = (tid & 7) * 16;  // 64 d x 128 s, 16 u16/thread
    int b = row0 >> 12, s0 = row0 & 4095;
    u16* dst = vbT + ((size_t)b * 64 + d) * 4096 + s0;
    // permuted store: position t_slot gets V row t_nat = pi(t_slot),
    // permutation applied within each 64-block (bit6 passes through)
#pragma unroll
    for (int g = 0; g < 4; ++g) {
      int ts = so + g * 4;
      int tn = (ts & 0x40) | (ts & 0x23) | ((ts & 4) << 2) | ((ts & 0x18) >> 1);
      *(u16x4*)(dst + ts) = *(const u16x4*)&vt[d * 136 + tn];
    }
  }
}

// ---------------------------------------------------------------------------
// Kernel 3: causal flash attention, 128 q-rows/block, 32 q-rows/wave.
// 2 LDS buffers (32 KB), <=8-tile chunks -> 1152 blocks. Depth-1 schedule:
// {vmcnt(0); barrier; prefetch(nxt); compute(cur)} — one barrier per tile,
// cur's loads issued a full compute phase earlier. Swapped QK^T
// (S^T = mfma(K,Q)); V pre-permuted so the PV A-fragment is each lane's own
// exp'd scores packed via v_cvt_pk_bf16_f32 — P never touches LDS.
// ---------------------------------------------------------------------------
__global__ __launch_bounds__(256) void attn_k(const u16* __restrict__ qb,
                                              const u16* __restrict__ kb,
                                              const u16* __restrict__ vbT,
                                              float* __restrict__ po,
                                              float* __restrict__ pl) {
  __shared__ __align__(16) u16 ks[2][4096];
  __shared__ __align__(16) u16 vs[2][4096];
  const int tid = threadIdx.x;
  const int wv = tid >> 6, ln = tid & 15, qd = (tid >> 4) & 3;
  const int id = blockIdx.x;  // 1152 blocks, longest chunks first
  const int b = id & 7;
  const int j = id >> 3;  // 0..143
  int qi = 31, acc = 0;
  for (;;) {
    int ncq = (2 * qi + 9) >> 3;
    if (acc + ncq <= j) { acc += ncq; --qi; } else break;
  }
  const int c = j - acc;                 // chunk index 0..nc-1
  const int ntiles = 2 * qi + 2;
  const int nc = (2 * qi + 9) >> 3;
  const int bas = ntiles / nc, rem = ntiles % nc;
  const int tstart = c * bas + (c < rem ? c : rem);
  const int tcount = bas + (c < rem ? 1 : 0);  // <= 8
  const int q0 = qi * 128;
  const int q0w = q0 + wv * 32;
  const int base = b * S_;
  const u16* kg = kb + (size_t)base * 64;
  const u16* vg = vbT + (size_t)b * 64 * 4096;

  bf16x8 qf[2][2];
#pragma unroll
  for (int qt = 0; qt < 2; ++qt) {
    const u16* qrow = qb + (size_t)(base + q0w + qt * 16 + ln) * 64;
    qf[qt][0] = *(const bf16x8*)(qrow + qd * 8);
    qf[qt][1] = *(const bf16x8*)(qrow + 32 + qd * 8);
  }
  const f32x4 z4 = {0.f, 0.f, 0.f, 0.f};
  f32x4 o0[4] = {z4, z4, z4, z4};
  f32x4 o1[4] = {z4, z4, z4, z4};
  float lq0 = 0.f, lq1 = 0.f;
  const int lr = (tid & 63) >> 3, csl = tid & 7;

  auto prefetch = [&](int bufi, int tile) {
    const u16* kt_ = kg + (size_t)tile * 4096;
    const u16* vt_ = vg + tile * 64;
#pragma unroll
    for (int i = 0; i < 2; ++i) {
      int r0 = wv * 16 + i * 8;
      int r = r0 + lr;
      int cc = csl ^ (r & 7);
      gl_lds16(kt_ + r * 64 + cc * 8, &ks[bufi][r0 * 64]);
      gl_lds16(vt_ + (size_t)r * 4096 + cc * 8, &vs[bufi][r0 * 64]);
    }
  };

  prefetch(0, tstart);
  int cur = 0;
  for (int it = 0; it < tcount; ++it) {
    // own cur-tile loads done -> barrier: everyone's cur landed AND all
    // waves finished computing from the other buffer (WAR-safe prefetch).
    asm volatile("s_waitcnt vmcnt(0)" ::: "memory");
    __builtin_amdgcn_s_barrier();
    if (it + 1 < tcount) prefetch(cur ^ 1, tstart + it + 1);
    const int t0a = (tstart + it) * 64;

    if (t0a <= q0w + 31) {  // wave-uniform: at least one live row
      f32x4 s0[4] = {z4, z4, z4, z4};
      f32x4 s1[4] = {z4, z4, z4, z4};
      // S^T = K * Q^T : lane holds col q=ln, rows t = nt*16 + qd*4 + r
      __builtin_amdgcn_s_setprio(1);
#pragma unroll
      for (int kc = 0; kc < 2; ++kc) {
        int cs = (kc * 4 + qd) ^ (ln & 7);
#pragma unroll
        for (int nt = 0; nt < 4; ++nt) {
          bf16x8 kf = *(const bf16x8*)&ks[cur][(nt * 16 + ln) * 64 + cs * 8];
          s0[nt] = __builtin_amdgcn_mfma_f32_16x16x32_bf16(kf, qf[0][kc], s0[nt], 0, 0, 0);
          s1[nt] = __builtin_amdgcn_mfma_f32_16x16x32_bf16(kf, qf[1][kc], s1[nt], 0, 0, 0);
        }
      }
      __builtin_amdgcn_s_setprio(0);
      if (t0a + 63 > q0w) {  // diagonal overlap: causal mask (t > q -> -inf)
#pragma unroll
        for (int nt = 0; nt < 4; ++nt) {
          int tg = t0a + nt * 16 + qd * 4;
#pragma unroll
          for (int r = 0; r < 4; ++r) {
            if (tg + r > q0w + ln) s0[nt][r] = -INFINITY;
            if (tg + r > q0w + 16 + ln) s1[nt][r] = -INFINITY;
          }
        }
      }
      // exp; pack in-register (V pre-permuted: A-frag = own values in order)
      float p0[4][4], p1[4][4];
#pragma unroll
      for (int nt = 0; nt < 4; ++nt)
#pragma unroll
        for (int r = 0; r < 4; ++r) {
          p0[nt][r] = __builtin_amdgcn_exp2f(s0[nt][r]);
          p1[nt][r] = __builtin_amdgcn_exp2f(s1[nt][r]);
          lq0 += p0[nt][r];
          lq1 += p1[nt][r];
        }
      unsigned pk0[8], pk1[8];
#pragma unroll
      for (int i = 0; i < 8; ++i) {  // word i: pair (p[i>>1][(i&1)*2], +1)
        int nt = i >> 1, rb = (i & 1) * 2;
        asm("v_cvt_pk_bf16_f32 %0, %1, %2"
            : "=v"(pk0[i]) : "v"(p0[nt][rb]), "v"(p0[nt][rb + 1]));
        asm("v_cvt_pk_bf16_f32 %0, %1, %2"
            : "=v"(pk1[i]) : "v"(p1[nt][rb]), "v"(p1[nt][rb + 1]));
      }
      // PV: A = packed P (registers), B = permuted-V fragments from LDS
      __builtin_amdgcn_s_setprio(1);
#pragma unroll
      for (int kc = 0; kc < 2; ++kc) {
        u32x4 w0 = {pk0[4 * kc], pk0[4 * kc + 1], pk0[4 * kc + 2], pk0[4 * kc + 3]};
        u32x4 w1 = {pk1[4 * kc], pk1[4 * kc + 1], pk1[4 * kc + 2], pk1[4 * kc + 3]};
        bf16x8 a0 = __builtin_bit_cast(bf16x8, w0);
        bf16x8 a1 = __builtin_bit_cast(bf16x8, w1);
        int cs = (kc * 4 + qd) ^ (ln & 7);
#pragma unroll
        for (int nt = 0; nt < 4; ++nt) {
          bf16x8 vf = *(const bf16x8*)&vs[cur][(nt * 16 + ln) * 64 + cs * 8];
          o0[nt] = __builtin_amdgcn_mfma_f32_16x16x32_bf16(a0, vf, o0[nt], 0, 0, 0);
          o1[nt] = __builtin_amdgcn_mfma_f32_16x16x32_bf16(a1, vf, o1[nt], 0, 0, 0);
        }
      }
      __builtin_amdgcn_s_setprio(0);
    }
    cur ^= 1;
  }

  // l-sums: per-lane partial is already per-q; reduce across the 4 qd lanes
  lq0 += __shfl_xor(lq0, 16);
  lq0 += __shfl_xor(lq0, 32);
  lq1 += __shfl_xor(lq1, 16);
  lq1 += __shfl_xor(lq1, 32);

  float* op = po + (size_t)c * 2097152;
  float* lpt = pl + (size_t)c * 32768;
#pragma unroll
  for (int r = 0; r < 4; ++r) {
    int row0 = base + q0w + qd * 4 + r;
    int row1 = row0 + 16;
#pragma unroll
    for (int nt = 0; nt < 4; ++nt) {
      op[(size_t)row0 * 64 + nt * 16 + ln] = o0[nt][r];
      op[(size_t)row1 * 64 + nt * 16 + ln] = o1[nt][r];
    }
  }
  if (qd == 0) {
    lpt[base + q0w + ln] = lq0;
    lpt[base + q0w + 16 + ln] = lq1;
  }
}

// ---------------------------------------------------------------------------
// Kernel 4: combine up to 8 partials: out = sum(o_c) / sum(l_c), c < nc(qi)
// ---------------------------------------------------------------------------
__global__ __launch_bounds__(256) void comb_k(const float* __restrict__ po,
                                              const float* __restrict__ pl,
                                              float* __restrict__ out) {
  int idx = blockIdx.x * 256 + threadIdx.x;  // 524288 threads
  int r = idx >> 4, d0 = (idx & 15) * 4;
  int qi = (r & 4095) >> 7;
  int nc = (2 * qi + 9) >> 3;
  const float* p = po + (size_t)r * 64 + d0;
  float4 a = *(const float4*)p;
  float l = pl[r];
  for (int cc = 1; cc < nc; ++cc) {
    float4 t = *(const float4*)(p + (size_t)cc * 2097152);
    a.x += t.x; a.y += t.y; a.z += t.z; a.w += t.w;
    l += pl[r + cc * 32768];
  }
  float inv = 1.0f / l;
  a.x *= inv; a.y *= inv; a.z *= inv; a.w *= inv;
  *(float4*)(out + (size_t)r * 64 + d0) = a;
}

// ---------------------------------------------------------------------------
extern "C" void kernel_launch(void* const* d_in, const int* in_sizes, int n_in,
                              void* d_out, int out_size, void* d_ws, size_t ws_size,
                              hipStream_t stream) {
  const float* x  = (const float*)d_in[0];
  const float* Wq = (const float*)d_in[1];
  const float* bq = (const float*)d_in[2];
  const float* Wk = (const float*)d_in[3];
  const float* bk = (const float*)d_in[4];
  const float* Wv = (const float*)d_in[5];
  const float* bv = (const float*)d_in[6];
  float* out = (float*)d_out;

  char* wsp = (char*)d_ws;
  u16* WbT = (u16*)wsp;                            //  294912 B
  u16* qb  = (u16*)(wsp + 294912);                 // 4 MiB
  u16* kb  = (u16*)(wsp + 4489216);                // 4 MiB
  u16* vbT = (u16*)(wsp + 8683520);                // 4 MiB (transposed+permuted)
  float* po = (float*)(wsp + 12877824);            // 8 x 8 MiB partial O slabs
  float* pl = (float*)(wsp + 79986688);            // 8 x 128 KiB partial l slabs

  hipLaunchKernelGGL(wconv_k, dim3(36), dim3(256), 0, stream, Wq, Wk, Wv, WbT);
  hipLaunchKernelGGL(qkv_k, dim3(256), dim3(512), 0, stream,
                     x, WbT, bq, bk, bv, qb, kb, vbT);
  hipLaunchKernelGGL(attn_k, dim3(1152), dim3(256), 0, stream,
                     qb, kb, vbT, po, pl);
  hipLaunchKernelGGL(comb_k, dim3(2048), dim3(256), 0, stream,
                     po, pl, out);
}